// Round 21
// baseline (264.503 us; speedup 1.0000x reference)
//
#include <hip/hip_runtime.h>
#include <math.h>

#define DD 100

// DPP quad-perm add (ctrl literal)
#define DPP_ADD(v, ctrl) ((v) + __int_as_float(__builtin_amdgcn_update_dpp( \
    0, __float_as_int(v), (ctrl), 0xf, 0xf, true)))

__device__ __forceinline__ float blo(unsigned u){
  union { unsigned i; float f; } c; c.i = u << 16; return c.f;
}
__device__ __forceinline__ float bhi(unsigned u){
  union { unsigned i; float f; } c; c.i = u & 0xFFFF0000u; return c.f;
}
__device__ __forceinline__ unsigned short f2bf(float f){
  unsigned u = __float_as_uint(f);
  unsigned r = (u + 0x7FFFu + ((u >> 16) & 1u)) >> 16;
  return (unsigned short)r;
}
// Phi(z) = 0.5*(1+erf(z/sqrt2)), Abramowitz-Stegun 7.1.26 (|err| ~1e-6)
__device__ __forceinline__ float phi_fast(float z){
  float x  = z * 0.70710678118654752440f;
  float ax = fabsf(x);
  float t  = __builtin_amdgcn_rcpf(1.0f + 0.3275911f*ax);
  float p  = t*(0.254829592f + t*(-0.284496736f + t*(1.421413741f
           + t*(-1.453152027f + t*1.061405429f))));
  float e  = __expf(-ax*ax);
  float erfv = copysignf(1.0f - p*e, x);
  return 0.5f*(1.0f + erfv);
}
__device__ __forceinline__ float4 relu4(float4 v){
  return make_float4(fmaxf(v.x,0.f), fmaxf(v.y,0.f), fmaxf(v.z,0.f), fmaxf(v.w,0.f));
}
#define GETJ4(v,j) ((j==0)?(v).x:(j==1)?(v).y:(j==2)?(v).z:(v).w)

// ---------------- Kernel 0: fold gate weights ------------------------------
// wfold[dim*90 + s*18 + e], s: 0=mem,1=rs,2=rr,3=x2,4=ns; e<9 wg, e>=9 wn.
// cat@W = mem@(W0+W3) + rs@(W1+W3) + rr@(W2+W3) + x2@W4 + ns@W5.
__global__ void k_fold(const float* __restrict__ wg, const float* __restrict__ wn,
                       float* __restrict__ wfold)
{
  int idx = blockIdx.x*256 + threadIdx.x;
  if (idx >= 9000) return;
  int dim = idx/90, r = idx%90, s = r/18, e = r%18;
  const float* W = (e < 9) ? wg : wn;
  int ee = (e < 9) ? e : e-9;
  int rowA = (s==0) ? dim : (s==1) ? 100+dim : (s==2) ? 200+dim
           : (s==3) ? 400+dim : 500+dim;
  float v = W[rowA*9 + ee] + ((s < 3) ? W[(300+dim)*9 + ee] : 0.f);
  wfold[idx] = v;
}

// ---------------- Kernel 1: gating -> gateinfo + loss partials ---------------
// 2 rows per 4-lane group (each weight b128 feeds 8 FMAs -> LDS-instr floor
// halved vs R15), engineered UNDER the 128-VGPR cliff that sank R12 (VGPR
// 148 -> 11% occ): loads for rows A and B are SEQUENTIAL phases reusing the
// same registers; only derived features (2x5 float4) + 36 accumulators live
// through the walk. 256-thread blocks (R15's proven shape), 128-row tiles,
// grid 704. Slot-remapped conflict-free weight LDS (R12-verified).
__global__ __launch_bounds__(256) void k_gate(
    const float* __restrict__ memf, const float* __restrict__ recr,
    const float* __restrict__ spar, const float* __restrict__ nsrc,
    const float* __restrict__ noise, const float* __restrict__ degc,
    const float* __restrict__ wfold, const int* __restrict__ degree,
    float4* __restrict__ gateinfo, float* __restrict__ partials, int B)
{
  __shared__ __align__(16) float sWF[100*92];   // 36.8 KB, slot-mapped
  __shared__ __align__(16) float sC0[DD], sC1[DD];
  __shared__ float sPart[4][18];

  for (int i = threadIdx.x; i < 9000; i += 256){
    int d = i/90, r = i%90;
    int slot = (d>>2) + 25*(d&3);
    sWF[slot*92 + r] = wfold[i];
  }
  for (int i = threadIdx.x; i < DD; i += 256){ sC0[i]=degc[2*i]; sC1[i]=degc[2*i+1]; }
  __syncthreads();

  const int wave = threadIdx.x >> 6, lane = threadIdx.x & 63;
  const int fq = lane & 3, rl = lane >> 2;
  const float4* sC04 = (const float4*)sC0;
  const float4* sC14 = (const float4*)sC1;

  float ldA[9], imA[9];
  #pragma unroll
  for (int e = 0; e < 9; e++){ ldA[e]=0.f; imA[e]=0.f; }

  const int rA = blockIdx.x*128 + wave*32 + rl*2;
  const int rB = rA + 1;
  const bool vA = rA < B, vB = rB < B;
  const int rcA = vA ? rA : B-1, rcB = vB ? rB : B-1;
  const float ldgA = __logf((float)degree[rcA] + 1.0f);
  const float ldgB = __logf((float)degree[rcB] + 1.0f);

  const float* pmA = memf + (size_t)rcA*DD;  const float* pmB = memf + (size_t)rcB*DD;
  const float* psA = spar + (size_t)rcA*4*DD;const float* psB = spar + (size_t)rcB*4*DD;
  const float* prA = recr + (size_t)rcA*4*DD;const float* prB = recr + (size_t)rcB*4*DD;
  const float* pnA = nsrc + (size_t)rcA*DD;  const float* pnB = nsrc + (size_t)rcB*DD;

  float cgA[9], cnA[9], cgB[9], cnB[9];
  #pragma unroll
  for (int e = 0; e < 9; e++){ cgA[e]=0.f; cnA[e]=0.f; cgB[e]=0.f; cnB[e]=0.f; }

  for (int k = 0; k < 7; k++){
    const int c = fq + 4*k;
    const float fz = (c < 25) ? 1.f : 0.f;
    const int ce = (c < 25) ? c : 0;
    const float4 c04 = sC04[ce], c14 = sC14[ce];

    // ---- phase A: load + derive (loader registers die at brace) ----
    float4 dA0, dA1, dA2, dA3, dA4;
    {
      float4 me = *(const float4*)(pmA + 4*ce);
      float4 s0 = *(const float4*)(psA + 0*DD + 4*ce);
      float4 s1 = *(const float4*)(psA + 1*DD + 4*ce);
      float4 s2 = *(const float4*)(psA + 2*DD + 4*ce);
      float4 s3 = *(const float4*)(psA + 3*DD + 4*ce);
      float4 r0 = *(const float4*)(prA + 0*DD + 4*ce);
      float4 r1 = *(const float4*)(prA + 1*DD + 4*ce);
      float4 r2 = *(const float4*)(prA + 2*DD + 4*ce);
      float4 r3 = *(const float4*)(prA + 3*DD + 4*ce);
      float4 nv = *(const float4*)(pnA + 4*ce);
      float4 m4 = relu4(me);
      float4 sc = make_float4(c04.x + ldgA*c14.x, c04.y + ldgA*c14.y,
                              c04.z + ldgA*c14.z, c04.w + ldgA*c14.w);
      float4 rs4 = make_float4((s0.x+s1.x+s2.x+s3.x)*0.25f*sc.x,
                               (s0.y+s1.y+s2.y+s3.y)*0.25f*sc.y,
                               (s0.z+s1.z+s2.z+s3.z)*0.25f*sc.z,
                               (s0.w+s1.w+s2.w+s3.w)*0.25f*sc.w);
      float4 a0 = relu4(r0), a1 = relu4(r1), a2 = relu4(r2), a3 = relu4(r3);
      float4 rr4 = make_float4((a0.x+a1.x+a2.x+a3.x)*0.25f,
                               (a0.y+a1.y+a2.y+a3.y)*0.25f,
                               (a0.z+a1.z+a2.z+a3.z)*0.25f,
                               (a0.w+a1.w+a2.w+a3.w)*0.25f);
      dA0 = make_float4(m4.x*fz, m4.y*fz, m4.z*fz, m4.w*fz);
      dA1 = make_float4(rs4.x*fz, rs4.y*fz, rs4.z*fz, rs4.w*fz);
      dA2 = make_float4(rr4.x*fz, rr4.y*fz, rr4.z*fz, rr4.w*fz);
      dA4 = make_float4(nv.x*fz, nv.y*fz, nv.z*fz, nv.w*fz);
      dA3 = make_float4(dA0.x*dA1.x*dA2.x, dA0.y*dA1.y*dA2.y,
                        dA0.z*dA1.z*dA2.z, dA0.w*dA1.w*dA2.w);
    }
    // ---- phase B: load + derive (reuses dead loader registers) ----
    float4 dB0, dB1, dB2, dB3, dB4;
    {
      float4 me = *(const float4*)(pmB + 4*ce);
      float4 s0 = *(const float4*)(psB + 0*DD + 4*ce);
      float4 s1 = *(const float4*)(psB + 1*DD + 4*ce);
      float4 s2 = *(const float4*)(psB + 2*DD + 4*ce);
      float4 s3 = *(const float4*)(psB + 3*DD + 4*ce);
      float4 r0 = *(const float4*)(prB + 0*DD + 4*ce);
      float4 r1 = *(const float4*)(prB + 1*DD + 4*ce);
      float4 r2 = *(const float4*)(prB + 2*DD + 4*ce);
      float4 r3 = *(const float4*)(prB + 3*DD + 4*ce);
      float4 nv = *(const float4*)(pnB + 4*ce);
      float4 m4 = relu4(me);
      float4 sc = make_float4(c04.x + ldgB*c14.x, c04.y + ldgB*c14.y,
                              c04.z + ldgB*c14.z, c04.w + ldgB*c14.w);
      float4 rs4 = make_float4((s0.x+s1.x+s2.x+s3.x)*0.25f*sc.x,
                               (s0.y+s1.y+s2.y+s3.y)*0.25f*sc.y,
                               (s0.z+s1.z+s2.z+s3.z)*0.25f*sc.z,
                               (s0.w+s1.w+s2.w+s3.w)*0.25f*sc.w);
      float4 a0 = relu4(r0), a1 = relu4(r1), a2 = relu4(r2), a3 = relu4(r3);
      float4 rr4 = make_float4((a0.x+a1.x+a2.x+a3.x)*0.25f,
                               (a0.y+a1.y+a2.y+a3.y)*0.25f,
                               (a0.z+a1.z+a2.z+a3.z)*0.25f,
                               (a0.w+a1.w+a2.w+a3.w)*0.25f);
      dB0 = make_float4(m4.x*fz, m4.y*fz, m4.z*fz, m4.w*fz);
      dB1 = make_float4(rs4.x*fz, rs4.y*fz, rs4.z*fz, rs4.w*fz);
      dB2 = make_float4(rr4.x*fz, rr4.y*fz, rr4.z*fz, rr4.w*fz);
      dB4 = make_float4(nv.x*fz, nv.y*fz, nv.z*fz, nv.w*fz);
      dB3 = make_float4(dB0.x*dB1.x*dB2.x, dB0.y*dB1.y*dB2.y,
                        dB0.z*dB1.z*dB2.z, dB0.w*dB1.w*dB2.w);
    }

    // ---- weight walk: one b128 stream feeds both rows (8 FMA / read) ----
    #pragma unroll
    for (int j = 0; j < 4; j++){
      const float a0 = GETJ4(dA0,j), a1 = GETJ4(dA1,j), a2 = GETJ4(dA2,j);
      const float a3 = GETJ4(dA3,j), a4 = GETJ4(dA4,j);
      const float b0 = GETJ4(dB0,j), b1 = GETJ4(dB1,j), b2 = GETJ4(dB2,j);
      const float b3 = GETJ4(dB3,j), b4 = GETJ4(dB4,j);
      const float4* wpj = (const float4*)(sWF + (ce + 25*j)*92);   // slot-remap
      #pragma unroll
      for (int tq = 0; tq < 23; tq++){
        float4 w = wpj[tq];
        #pragma unroll
        for (int u = 0; u < 4; u++){
          const int ww = 4*tq + u;
          if (ww < 90){
            const int seg = ww/18, e = ww%18;
            float wv = (u==0)?w.x:(u==1)?w.y:(u==2)?w.z:w.w;
            float dA = (seg==0)?a0:(seg==1)?a1:(seg==2)?a2:(seg==3)?a3:a4;
            float dB = (seg==0)?b0:(seg==1)?b1:(seg==2)?b2:(seg==3)?b3:b4;
            if (e < 9){ cgA[e] += dA*wv; cgB[e] += dB*wv; }
            else      { cnA[e-9] += dA*wv; cnB[e-9] += dB*wv; }
          }
        }
      }
    }
  }

  // quad reduce: all 4 lanes of a group hold full sums for BOTH rows
  #pragma unroll
  for (int e = 0; e < 9; e++){
    cgA[e] = DPP_ADD(cgA[e], 0xB1); cgA[e] = DPP_ADD(cgA[e], 0x4E);
    cnA[e] = DPP_ADD(cnA[e], 0xB1); cnA[e] = DPP_ADD(cnA[e], 0x4E);
    cgB[e] = DPP_ADD(cgB[e], 0xB1); cgB[e] = DPP_ADD(cgB[e], 0x4E);
    cnB[e] = DPP_ADD(cnB[e], 0xB1); cnB[e] = DPP_ADD(cnB[e], 0x4E);
  }

  // lanes fq<2 finalize row A, fq>=2 finalize row B (static selects)
  const bool selB = (fq >= 2);
  const int rowS = selB ? rB : rA;
  const bool vS = rowS < B;
  const int rcS = vS ? rowS : B-1;
  float fg[9], fn[9];
  #pragma unroll
  for (int e = 0; e < 9; e++){
    fg[e] = selB ? cgB[e] : cgA[e];
    fn[e] = selB ? cnB[e] : cnA[e];
  }

  float sdv[9], rsd[9], nz[9];
  #pragma unroll
  for (int e = 0; e < 9; e++){
    float x = fn[e];
    float spl = fmaxf(x, 0.f) + __logf(1.0f + __expf(-fabsf(x)));
    sdv[e] = spl + 0.01f;
    rsd[e] = __builtin_amdgcn_rcpf(sdv[e]);
    nz[e]  = fg[e] + noise[(size_t)rcS*9 + e] * sdv[e];
  }
  float v1 = -3.402823e38f, v2 = v1, v3 = v1; int i1 = -1, i2 = -1;
  #pragma unroll
  for (int e = 0; e < 9; e++){
    float v = nz[e];
    if (v > v1){ v3=v2; v2=v1; i2=i1; v1=v; i1=e; }
    else if (v > v2){ v3=v2; v2=v; i2=e; }
    else if (v > v3){ v3=v; }
  }
  float tt = __expf(v2 - v1);
  float g1 = __builtin_amdgcn_rcpf(1.0f + tt);
  float g2 = tt*g1;

  float ld[9], im[9];
  #pragma unroll
  for (int e = 0; e < 9; e++){
    float thr = (nz[e] > v3) ? v3 : v2;
    float z = (fg[e] - thr)*rsd[e] - 0.1f;               // GATE_MEAN = 0.1
    ld[e] = vS ? phi_fast(z) : 0.f;
    im[e] = vS ? ((e==i1) ? g1 : ((e==i2) ? g2 : 0.f)) : 0.f;
  }
  if ((fq & 1) == 0 && vS)   // fq==0 writes row A, fq==2 writes row B
    gateinfo[rowS] = make_float4(g1, g2, __int_as_float(i1), __int_as_float(i2));

  // butterfly: {4,8,16,32} sums the 16 groups; {2} merges row parities
  // (fq0/1 and fq2/3 are duplicates -> NO off=1).
  #pragma unroll
  for (int e = 0; e < 9; e++){
    #pragma unroll
    for (int off = 4; off < 64; off <<= 1){
      ld[e] += __shfl_xor(ld[e], off, 64);
      im[e] += __shfl_xor(im[e], off, 64);
    }
    ld[e] += __shfl_xor(ld[e], 2, 64);
    im[e] += __shfl_xor(im[e], 2, 64);
  }
  if (lane == 0){
    #pragma unroll
    for (int e = 0; e < 9; e++){ sPart[wave][e] = im[e]; sPart[wave][9+e] = ld[e]; }
  }
  __syncthreads();
  if (threadIdx.x < 18){
    float s = sPart[0][threadIdx.x] + sPart[1][threadIdx.x]
            + sPart[2][threadIdx.x] + sPart[3][threadIdx.x];
    partials[blockIdx.x*18 + threadIdx.x] = s;
  }
}

// ---------------- Kernel 2: expert mix -> outm (reads only chosen experts) ---
__global__ __launch_bounds__(256) void k_mix(
    const float* __restrict__ memf, const float* __restrict__ recr,
    const float* __restrict__ spar, const float* __restrict__ degc,
    const int* __restrict__ degree, const float4* __restrict__ gateinfo,
    float* __restrict__ outm, int B)
{
  const int total = B*25;
  for (int idx = blockIdx.x*256 + threadIdx.x; idx < total; idx += gridDim.x*256){
    int row = idx / 25, q = idx - row*25;
    float4 gi = gateinfo[row];
    float gv[2] = {gi.x, gi.y};
    int   ei[2] = {__float_as_int(gi.z), __float_as_int(gi.w)};
    float4 acc = make_float4(0.f,0.f,0.f,0.f);
    #pragma unroll
    for (int s = 0; s < 2; s++){
      int e = ei[s]; float g = gv[s];
      float4 v;
      if (e == 0){
        v = relu4(*(const float4*)(memf + (size_t)row*DD + 4*q));
      } else if (e < 5){
        float ldg = __logf((float)degree[row] + 1.0f);
        float4 ca = *(const float4*)(degc + 8*q);       // c0,c1,c0,c1
        float4 cb = *(const float4*)(degc + 8*q + 4);
        float4 sv = *(const float4*)(spar + ((size_t)row*4 + (e-1))*DD + 4*q);
        v = make_float4(sv.x*(ca.x + ldg*ca.y), sv.y*(ca.z + ldg*ca.w),
                        sv.z*(cb.x + ldg*cb.y), sv.w*(cb.z + ldg*cb.w));
      } else {
        v = relu4(*(const float4*)(recr + ((size_t)row*4 + (e-5))*DD + 4*q));
      }
      acc.x += g*v.x; acc.y += g*v.y; acc.z += g*v.z; acc.w += g*v.w;
    }
    ((float4*)outm)[(size_t)row*25 + q] = acc;
  }
}

// ---------------- Kernel 3: deterministic loss reduction ---------------------
__global__ __launch_bounds__(1024) void k_loss(const float* __restrict__ partials,
                                               int nblk, float* __restrict__ dloss)
{
  __shared__ float sS[18][57];
  int t = threadIdx.x;
  if (t < 1008){
    int k = t % 18, c = t / 18;   // 56 chunks
    float s = 0.f;
    for (int b = c; b < nblk; b += 56) s += partials[b*18 + k];
    sS[k][c] = s;
  }
  __syncthreads();
  if (t < 18){
    float tot = 0.f;
    #pragma unroll
    for (int c = 0; c < 56; c++) tot += sS[t][c];
    sS[t][56] = tot;
  }
  __syncthreads();
  if (t == 0){
    float mi = 0.f, ml = 0.f;
    #pragma unroll
    for (int e = 0; e < 9; e++){ mi += sS[e][56]; ml += sS[9+e][56]; }
    mi *= (1.f/9.f); ml *= (1.f/9.f);
    float vi = 0.f, vl = 0.f;
    #pragma unroll
    for (int e = 0; e < 9; e++){
      float a = sS[e][56]   - mi; vi += a*a;
      float b = sS[9+e][56] - ml; vl += b*b;
    }
    vi *= (1.f/8.f); vl *= (1.f/8.f);   // ddof=1, n=9
    *dloss = 0.4f * (vi/(mi*mi + 1e-10f) + vl/(ml*ml + 1e-10f));
  }
}

// ---------------- Kernel 4: link-prediction head -----------------------------
__global__ __launch_bounds__(512) void k_edge(
    const float* __restrict__ om,
    const float* __restrict__ sw, const float* __restrict__ sb,
    const float* __restrict__ dw, const float* __restrict__ db,
    const float* __restrict__ ow, const float* __restrict__ ob,
    float* __restrict__ dout, int NE)
{
  __shared__ __align__(4) unsigned short sSW[DD*102];
  __shared__ __align__(4) unsigned short sDW[DD*102];
  __shared__ float sSB[DD], sDB[DD], sOW[DD];

  for (int i = threadIdx.x; i < DD*DD; i += 512){
    int k = i / DD, d = i % DD;
    sSW[d*102 + k] = f2bf(sw[i]);
    sDW[d*102 + k] = f2bf(dw[i]);
  }
  for (int i = threadIdx.x; i < DD; i += 512){ sSB[i]=sb[i]; sDB[i]=db[i]; sOW[i]=ow[i]; }
  __syncthreads();

  const int wave = threadIdx.x >> 6, lane = threadIdx.x & 63;
  const int grp = blockIdx.x*8 + wave;
  const int e0 = grp*4;
  if (e0 >= NE) return;
  const int e0u = __builtin_amdgcn_readfirstlane(e0);
  const float* oS = om + (size_t)e0u*DD;
  const float* oP = om + ((size_t)(NE  + e0u))*DD;
  const float* oN = om + ((size_t)(2*NE + e0u))*DD;
  const int d0 = lane, d1 = lane + 64;
  const bool h1 = (d1 < DD);
  const int dc1 = h1 ? d1 : 0;

  float aS[4][2], aP[4][2], aN[4][2];
  #pragma unroll
  for (int r = 0; r < 4; r++){
    aS[r][0]=0.f; aS[r][1]=0.f; aP[r][0]=0.f; aP[r][1]=0.f; aN[r][0]=0.f; aN[r][1]=0.f;
  }

  for (int k = 0; k < DD; k += 4){
    unsigned uA = *(const unsigned*)&sSW[d0 *102 + k];
    unsigned uB = *(const unsigned*)&sSW[d0 *102 + k + 2];
    unsigned uC = *(const unsigned*)&sSW[dc1*102 + k];
    unsigned uD = *(const unsigned*)&sSW[dc1*102 + k + 2];
    unsigned uE = *(const unsigned*)&sDW[d0 *102 + k];
    unsigned uF = *(const unsigned*)&sDW[d0 *102 + k + 2];
    unsigned uG = *(const unsigned*)&sDW[dc1*102 + k];
    unsigned uH = *(const unsigned*)&sDW[dc1*102 + k + 2];
    float wS00=blo(uA), wS01=bhi(uA), wS02=blo(uB), wS03=bhi(uB);
    float wS10=blo(uC), wS11=bhi(uC), wS12=blo(uD), wS13=bhi(uD);
    float wD00=blo(uE), wD01=bhi(uE), wD02=blo(uF), wD03=bhi(uF);
    float wD10=blo(uG), wD11=bhi(uG), wD12=blo(uH), wD13=bhi(uH);
    #pragma unroll
    for (int r = 0; r < 4; r++){
      float4 ov = *(const float4*)(oS + r*DD + k);
      float4 pv = *(const float4*)(oP + r*DD + k);
      float4 nv = *(const float4*)(oN + r*DD + k);
      aS[r][0] += ov.x*wS00 + ov.y*wS01 + ov.z*wS02 + ov.w*wS03;
      aS[r][1] += ov.x*wS10 + ov.y*wS11 + ov.z*wS12 + ov.w*wS13;
      aP[r][0] += pv.x*wD00 + pv.y*wD01 + pv.z*wD02 + pv.w*wD03;
      aP[r][1] += pv.x*wD10 + pv.y*wD11 + pv.z*wD12 + pv.w*wD13;
      aN[r][0] += nv.x*wD00 + nv.y*wD01 + nv.z*wD02 + nv.w*wD03;
      aN[r][1] += nv.x*wD10 + nv.y*wD11 + nv.z*wD12 + nv.w*wD13;
    }
  }

  float owa = sOW[d0], owb = sOW[dc1];
  float sba = sSB[d0], sbb = sSB[dc1];
  float dba = sDB[d0], dbb = sDB[dc1];
  float ob0 = ob[0];
  #pragma unroll
  for (int r = 0; r < 4; r++){
    float hs0 = aS[r][0] + sba, hp0 = aP[r][0] + dba, hn0 = aN[r][0] + dba;
    float tp = fmaxf(hs0 + hp0, 0.f)*owa;
    float tn = fmaxf(hs0 + hn0, 0.f)*owa;
    if (h1){
      float hs1 = aS[r][1] + sbb, hp1 = aP[r][1] + dbb, hn1 = aN[r][1] + dbb;
      tp += fmaxf(hs1 + hp1, 0.f)*owb;
      tn += fmaxf(hs1 + hn1, 0.f)*owb;
    }
    #pragma unroll
    for (int off = 32; off > 0; off >>= 1){
      tp += __shfl_xor(tp, off, 64);
      tn += __shfl_xor(tn, off, 64);
    }
    if (lane == 0){
      dout[e0 + r]      = tp + ob0;
      dout[NE + e0 + r] = tn + ob0;
    }
  }
}

extern "C" void kernel_launch(void* const* d_in, const int* in_sizes, int n_in,
                              void* d_out, int out_size, void* d_ws, size_t ws_size,
                              hipStream_t stream)
{
  (void)n_in; (void)out_size; (void)ws_size;
  const float* memf  = (const float*)d_in[0];
  const float* recr  = (const float*)d_in[1];
  const float* spar  = (const float*)d_in[2];
  const float* nsrc  = (const float*)d_in[3];
  const float* noise = (const float*)d_in[4];
  const float* degc  = (const float*)d_in[5];
  const float* wg    = (const float*)d_in[6];
  const float* wn    = (const float*)d_in[7];
  const float* sw    = (const float*)d_in[8];
  const float* sb    = (const float*)d_in[9];
  const float* dw    = (const float*)d_in[10];
  const float* db    = (const float*)d_in[11];
  const float* ow    = (const float*)d_in[12];
  const float* ob    = (const float*)d_in[13];
  const int*   deg   = (const int*)d_in[14];

  const int B  = in_sizes[0] / DD;     // 90000
  const int NE = B / 3;                // 30000
  const int blocksA = (B + 127) / 128; // 704 (128-row tiles, 32 rows/wave)

  float4* gateinfo = (float4*)d_ws;                      // B float4
  float*  outm     = (float*)(gateinfo + B);             // B*DD floats
  float*  partials = outm + (size_t)B*DD;                // blocksA*18
  float*  wfold    = partials + (size_t)blocksA*18;      // 9000 floats
  float*  dout     = (float*)d_out;

  k_fold<<<dim3(36), dim3(256), 0, stream>>>(wg, wn, wfold);
  k_gate<<<dim3(blocksA), dim3(256), 0, stream>>>(memf, recr, spar, nsrc, noise,
                                                  degc, wfold, deg, gateinfo,
                                                  partials, B);
  k_mix<<<dim3(2048), dim3(256), 0, stream>>>(memf, recr, spar, degc, deg,
                                              gateinfo, outm, B);
  k_loss<<<dim3(1), dim3(1024), 0, stream>>>(partials, blocksA, dout + 2*NE);
  const int blocks2 = (NE/4 + 7) / 8;  // 938
  k_edge<<<dim3(blocks2), dim3(512), 0, stream>>>(outm, sw, sb, dw, db, ow, ob, dout, NE);
}